// Round 5
// baseline (950.989 us; speedup 1.0000x reference)
//
#include <hip/hip_runtime.h>

typedef __attribute__((ext_vector_type(8))) short short8;
typedef __attribute__((ext_vector_type(4))) float f32x4;
typedef __attribute__((ext_vector_type(4))) unsigned short ushort4_t;
typedef unsigned short ushort;
typedef unsigned int uint;

#define H 16
#define DK 64
#define DX 1024
#define BB 2
#define LQ 2048
#define LK 2048
#define NTOK (BB * LQ)   // 4096
#define NBH (BB * H)     // 32

__device__ __forceinline__ ushort f2bf(float x) {
  uint u = __float_as_uint(x);
  u = (u + 0x7FFFu + ((u >> 16) & 1u)) >> 16;  // RNE
  return (ushort)u;
}

// ---------------------------------------------------------------- mask pack
__global__ __launch_bounds__(256) void pack_mask_k(const int* __restrict__ m,
                                                   uint* __restrict__ packed) {
  int idx = blockIdx.x * 256 + threadIdx.x;
  unsigned long long b = __ballot(m[idx] != 0);
  int lane = threadIdx.x & 63;
  if ((lane & 31) == 0)
    packed[idx >> 5] = (uint)((lane & 32) ? (b >> 32) : b);
}

// ------------------------------------------------------------- f32 -> bf16
__global__ __launch_bounds__(256) void convert_in_k(
    const float* __restrict__ q, const float* __restrict__ k,
    const float* __restrict__ v, ushort* __restrict__ qb,
    ushort* __restrict__ kb, ushort* __restrict__ vb) {
  const float* src = (blockIdx.z == 0) ? q : (blockIdx.z == 1) ? k : v;
  ushort* dst = (blockIdx.z == 0) ? qb : (blockIdx.z == 1) ? kb : vb;
  size_t idx = ((size_t)blockIdx.x * 256 + threadIdx.x) * 4;
  f32x4 val = *(const f32x4*)&src[idx];
  ushort4_t o;
  o[0] = f2bf(val[0]); o[1] = f2bf(val[1]);
  o[2] = f2bf(val[2]); o[3] = f2bf(val[3]);
  *(ushort4_t*)&dst[idx] = o;
}

// --------------------------------------- weights: W[k][n] f32 -> Wt[n][k] bf16
__global__ __launch_bounds__(256) void transpose_w_k(
    const float* __restrict__ w0, const float* __restrict__ w1,
    const float* __restrict__ w2, const float* __restrict__ w3,
    ushort* __restrict__ wt) {
  const int z = blockIdx.z;
  const float* W = (z == 0) ? w0 : (z == 1) ? w1 : (z == 2) ? w2 : w3;
  ushort* O = wt + (size_t)z * DX * DX;
  const int kb = blockIdx.x << 6, nb = blockIdx.y << 6;
  __shared__ ushort tile[64][72];
  for (int idx = threadIdx.x; idx < 4096; idx += 256) {
    int i = idx >> 6, j = idx & 63;
    tile[j][i] = f2bf(W[(size_t)(kb + i) * DX + nb + j]);
  }
  __syncthreads();
  for (int idx = threadIdx.x; idx < 4096; idx += 256) {
    int j = idx >> 6, i = idx & 63;
    O[(size_t)(nb + j) * DX + kb + i] = tile[j][i];
  }
}

// ----------------------------------------------- QKV projection GEMM (bf16)
// C[M=4096, N=1024] = A[M,K=1024] * Bt[N,K]^T ; tile 128x64, 4 waves
__global__ __launch_bounds__(256) void gemm_qkv_k(
    const ushort* __restrict__ qb, const ushort* __restrict__ kb,
    const ushort* __restrict__ vb, const ushort* __restrict__ wt,
    const float* __restrict__ biasq, const float* __restrict__ biask,
    const float* __restrict__ biasv,
    ushort* __restrict__ Qh, ushort* __restrict__ Kh, ushort* __restrict__ Vt) {
  const int z = blockIdx.z;
  const ushort* A = (z == 0) ? qb : (z == 1) ? kb : vb;
  const ushort* Bt = wt + (size_t)z * DX * DX;
  const float* bias = (z == 0) ? biasq : (z == 1) ? biask : biasv;

  const int tid = threadIdx.x;
  const int w = tid >> 6, l = tid & 63, lr = l & 15, lg = l >> 4;
  const int mbase = blockIdx.y << 7, nbase = blockIdx.x << 6;

  __shared__ ushort As[128][72];
  __shared__ ushort Bs[64][72];

  const f32x4 fz = {0.f, 0.f, 0.f, 0.f};
  f32x4 acc[2][4] = {{fz, fz, fz, fz}, {fz, fz, fz, fz}};

  for (int kt = 0; kt < DX / 64; ++kt) {
    const int kbase = kt << 6;
    for (int c = tid; c < 1536; c += 256) {
      if (c < 1024) {
        int r = c >> 3, c8 = (c & 7) << 3;
        *(uint4*)&As[r][c8] = *(const uint4*)&A[(size_t)(mbase + r) * DX + kbase + c8];
      } else {
        int cc = c - 1024;
        int r = cc >> 3, c8 = (cc & 7) << 3;
        *(uint4*)&Bs[r][c8] = *(const uint4*)&Bt[(size_t)(nbase + r) * DX + kbase + c8];
      }
    }
    __syncthreads();
    short8 bfr[4][2];
#pragma unroll
    for (int nf = 0; nf < 4; ++nf) {
      bfr[nf][0] = *(const short8*)&Bs[nf * 16 + lr][lg * 8];
      bfr[nf][1] = *(const short8*)&Bs[nf * 16 + lr][32 + lg * 8];
    }
#pragma unroll
    for (int mf = 0; mf < 2; ++mf) {
      short8 a0 = *(const short8*)&As[w * 32 + mf * 16 + lr][lg * 8];
      short8 a1 = *(const short8*)&As[w * 32 + mf * 16 + lr][32 + lg * 8];
#pragma unroll
      for (int nf = 0; nf < 4; ++nf) {
        acc[mf][nf] = __builtin_amdgcn_mfma_f32_16x16x32_bf16(a0, bfr[nf][0], acc[mf][nf], 0, 0, 0);
        acc[mf][nf] = __builtin_amdgcn_mfma_f32_16x16x32_bf16(a1, bfr[nf][1], acc[mf][nf], 0, 0, 0);
      }
    }
    __syncthreads();
  }

  float biasn[4];
#pragma unroll
  for (int nf = 0; nf < 4; ++nf) biasn[nf] = bias[nbase + nf * 16 + lr];

#pragma unroll
  for (int mf = 0; mf < 2; ++mf) {
#pragma unroll
    for (int nf = 0; nf < 4; ++nf) {
#pragma unroll
      for (int j = 0; j < 4; ++j) {
        int r = mbase + w * 32 + mf * 16 + lg * 4 + j;
        int n = nbase + nf * 16 + lr;
        float val = acc[mf][nf][j] + biasn[nf];
        int b_ = r >> 11, ltok = r & 2047, h_ = n >> 6, d_ = n & 63;
        if (z == 2)
          Vt[((size_t)(b_ * H + h_) * DK + d_) * LK + ltok] = f2bf(val);
        else {
          ushort* O = (z == 0) ? Qh : Kh;
          O[((size_t)(b_ * H + h_) * LQ + ltok) * DK + d_] = f2bf(val);
        }
      }
    }
  }
}

// ------------------------------------------------------------ fused attention
// grid (LQ/64, NBH), 256 threads. Two passes: A = rowsums; B = write attn + PV.
__global__ __launch_bounds__(256) void attn_k(
    const ushort* __restrict__ Qh, const ushort* __restrict__ Kh,
    const ushort* __restrict__ Vt, const uint* __restrict__ mpak,
    float* __restrict__ attn, ushort* __restrict__ aout) {
  const int tid = threadIdx.x;
  const int w = tid >> 6, l = tid & 63, lr = l & 15, lg = l >> 4;
  const int bh = blockIdx.y;
  const int qbase = blockIdx.x << 6;
  const int mb = bh & (BB - 1);  // faithful quirk: mask batch = (b*H+h) % B

  __shared__ ushort Qs[64][72];
  __shared__ ushort Ks[64][72];
  __shared__ ushort Vts[64][72];
  ushort (*Ps)[72] = Qs;  // Q staging reused as P tile after qa regs loaded

  const ushort* Qg = Qh + ((size_t)bh * LQ + qbase) * DK;
  for (int c = tid; c < 512; c += 256) {
    int r = c >> 3, c8 = (c & 7) << 3;
    *(uint4*)&Qs[r][c8] = *(const uint4*)&Qg[r * DK + c8];
  }
  __syncthreads();
  short8 qa0 = *(const short8*)&Qs[w * 16 + lr][lg * 8];
  short8 qa1 = *(const short8*)&Qs[w * 16 + lr][32 + lg * 8];
  __syncthreads();

  const ushort* Kg = Kh + (size_t)bh * LK * DK;
  const ushort* Vg = Vt + (size_t)bh * DK * LK;
  const uint* mr = mpak + (size_t)mb * LQ * (LK / 32);
  const int qrow0 = qbase + w * 16 + lg * 4;
  const f32x4 fz = {0.f, 0.f, 0.f, 0.f};

  float rs[4] = {0.f, 0.f, 0.f, 0.f};

  for (int kt = 0; kt < LK / 64; ++kt) {
    const int kbase = kt << 6;
    for (int c = tid; c < 512; c += 256) {
      int r = c >> 3, c8 = (c & 7) << 3;
      *(uint4*)&Ks[r][c8] = *(const uint4*)&Kg[(size_t)(kbase + r) * DK + c8];
    }
    __syncthreads();
    f32x4 acc[4] = {fz, fz, fz, fz};
#pragma unroll
    for (int nf = 0; nf < 4; ++nf) {
      short8 kb0 = *(const short8*)&Ks[nf * 16 + lr][lg * 8];
      short8 kb1 = *(const short8*)&Ks[nf * 16 + lr][32 + lg * 8];
      acc[nf] = __builtin_amdgcn_mfma_f32_16x16x32_bf16(qa0, kb0, acc[nf], 0, 0, 0);
      acc[nf] = __builtin_amdgcn_mfma_f32_16x16x32_bf16(qa1, kb1, acc[nf], 0, 0, 0);
    }
    const int kw = kbase >> 5;
#pragma unroll
    for (int j = 0; j < 4; ++j) {
      const uint* mp = mr + (size_t)(qrow0 + j) * (LK / 32) + kw;
      uint mw0 = mp[0], mw1 = mp[1];
#pragma unroll
      for (int nf = 0; nf < 4; ++nf) {
        uint mw = (nf < 2) ? mw0 : mw1;
        uint bit = ((nf & 1) << 4) + lr;
        if (!((mw >> bit) & 1u)) rs[j] += __expf(acc[nf][j] * 0.125f);
      }
    }
    __syncthreads();
  }

#pragma unroll
  for (int off = 1; off < 16; off <<= 1) {
#pragma unroll
    for (int j = 0; j < 4; ++j) rs[j] += __shfl_xor(rs[j], off);
  }
  float inv[4];
#pragma unroll
  for (int j = 0; j < 4; ++j) inv[j] = 1.f / rs[j];

  f32x4 oacc[4] = {fz, fz, fz, fz};
  float* attnO = attn + (size_t)bh * LQ * LK;

  for (int kt = 0; kt < LK / 64; ++kt) {
    const int kbase = kt << 6;
    for (int c = tid; c < 1024; c += 256) {
      int cc = c & 511;
      int r = cc >> 3, c8 = (cc & 7) << 3;
      if (c < 512)
        *(uint4*)&Ks[r][c8] = *(const uint4*)&Kg[(size_t)(kbase + r) * DK + c8];
      else
        *(uint4*)&Vts[r][c8] = *(const uint4*)&Vg[(size_t)r * LK + kbase + c8];
    }
    __syncthreads();
    f32x4 acc[4] = {fz, fz, fz, fz};
#pragma unroll
    for (int nf = 0; nf < 4; ++nf) {
      short8 kb0 = *(const short8*)&Ks[nf * 16 + lr][lg * 8];
      short8 kb1 = *(const short8*)&Ks[nf * 16 + lr][32 + lg * 8];
      acc[nf] = __builtin_amdgcn_mfma_f32_16x16x32_bf16(qa0, kb0, acc[nf], 0, 0, 0);
      acc[nf] = __builtin_amdgcn_mfma_f32_16x16x32_bf16(qa1, kb1, acc[nf], 0, 0, 0);
    }
    const int kw = kbase >> 5;
#pragma unroll
    for (int j = 0; j < 4; ++j) {
      const uint* mp = mr + (size_t)(qrow0 + j) * (LK / 32) + kw;
      uint mw0 = mp[0], mw1 = mp[1];
      float* arow = attnO + (size_t)(qrow0 + j) * LK + kbase;
#pragma unroll
      for (int nf = 0; nf < 4; ++nf) {
        uint mw = (nf < 2) ? mw0 : mw1;
        uint bit = ((nf & 1) << 4) + lr;
        float p = ((mw >> bit) & 1u) ? 0.f : __expf(acc[nf][j] * 0.125f) * inv[j];
        arow[nf * 16 + lr] = p;                              // f32 attn out
        Ps[w * 16 + lg * 4 + j][nf * 16 + lr] = f2bf(p);     // bf16 for PV
      }
    }
    __syncthreads();
    short8 pa0 = *(const short8*)&Ps[w * 16 + lr][lg * 8];
    short8 pa1 = *(const short8*)&Ps[w * 16 + lr][32 + lg * 8];
#pragma unroll
    for (int nf = 0; nf < 4; ++nf) {
      short8 vb0 = *(const short8*)&Vts[nf * 16 + lr][lg * 8];
      short8 vb1 = *(const short8*)&Vts[nf * 16 + lr][32 + lg * 8];
      oacc[nf] = __builtin_amdgcn_mfma_f32_16x16x32_bf16(pa0, vb0, oacc[nf], 0, 0, 0);
      oacc[nf] = __builtin_amdgcn_mfma_f32_16x16x32_bf16(pa1, vb1, oacc[nf], 0, 0, 0);
    }
    __syncthreads();
  }

  const int b_ = bh >> 4, h_ = bh & 15;
#pragma unroll
  for (int nf = 0; nf < 4; ++nf) {
#pragma unroll
    for (int j = 0; j < 4; ++j) {
      int t = b_ * LQ + qrow0 + j;
      aout[(size_t)t * (H * DK) + h_ * DK + nf * 16 + lr] = f2bf(oacc[nf][j]);
    }
  }
}

// -------------------------------------------------- output projection GEMM
__global__ __launch_bounds__(256) void gemm_out_k(
    const ushort* __restrict__ A, const ushort* __restrict__ Bt,
    float* __restrict__ proj) {
  const int tid = threadIdx.x;
  const int w = tid >> 6, l = tid & 63, lr = l & 15, lg = l >> 4;
  const int mbase = blockIdx.y << 7, nbase = blockIdx.x << 6;

  __shared__ ushort As[128][72];
  __shared__ ushort Bs[64][72];

  const f32x4 fz = {0.f, 0.f, 0.f, 0.f};
  f32x4 acc[2][4] = {{fz, fz, fz, fz}, {fz, fz, fz, fz}};

  for (int kt = 0; kt < DX / 64; ++kt) {
    const int kbase = kt << 6;
    for (int c = tid; c < 1536; c += 256) {
      if (c < 1024) {
        int r = c >> 3, c8 = (c & 7) << 3;
        *(uint4*)&As[r][c8] = *(const uint4*)&A[(size_t)(mbase + r) * DX + kbase + c8];
      } else {
        int cc = c - 1024;
        int r = cc >> 3, c8 = (cc & 7) << 3;
        *(uint4*)&Bs[r][c8] = *(const uint4*)&Bt[(size_t)(nbase + r) * DX + kbase + c8];
      }
    }
    __syncthreads();
    short8 bfr[4][2];
#pragma unroll
    for (int nf = 0; nf < 4; ++nf) {
      bfr[nf][0] = *(const short8*)&Bs[nf * 16 + lr][lg * 8];
      bfr[nf][1] = *(const short8*)&Bs[nf * 16 + lr][32 + lg * 8];
    }
#pragma unroll
    for (int mf = 0; mf < 2; ++mf) {
      short8 a0 = *(const short8*)&As[w * 32 + mf * 16 + lr][lg * 8];
      short8 a1 = *(const short8*)&As[w * 32 + mf * 16 + lr][32 + lg * 8];
#pragma unroll
      for (int nf = 0; nf < 4; ++nf) {
        acc[mf][nf] = __builtin_amdgcn_mfma_f32_16x16x32_bf16(a0, bfr[nf][0], acc[mf][nf], 0, 0, 0);
        acc[mf][nf] = __builtin_amdgcn_mfma_f32_16x16x32_bf16(a1, bfr[nf][1], acc[mf][nf], 0, 0, 0);
      }
    }
    __syncthreads();
  }

#pragma unroll
  for (int mf = 0; mf < 2; ++mf) {
#pragma unroll
    for (int nf = 0; nf < 4; ++nf) {
#pragma unroll
      for (int j = 0; j < 4; ++j) {
        int r = mbase + w * 32 + mf * 16 + lg * 4 + j;
        int n = nbase + nf * 16 + lr;
        proj[(size_t)r * DX + n] = acc[mf][nf][j];
      }
    }
  }
}

// ---------------------------------------------- residual + bias + LayerNorm
__global__ __launch_bounds__(256) void ln_k(
    const float* __restrict__ proj, const float* __restrict__ X,
    const float* __restrict__ wo_b, const float* __restrict__ g,
    const float* __restrict__ beta, float* __restrict__ out) {
  const int t = blockIdx.x, tid = threadIdx.x;
  __shared__ float redA[4], redB[4];
  float x[4];
  float s = 0.f;
#pragma unroll
  for (int i = 0; i < 4; ++i) {
    int c = tid + (i << 8);
    x[i] = proj[(size_t)t * DX + c] + wo_b[c] + X[(size_t)t * DX + c];
    s += x[i];
  }
#pragma unroll
  for (int off = 32; off > 0; off >>= 1) s += __shfl_xor(s, off);
  if ((tid & 63) == 0) redA[tid >> 6] = s;
  __syncthreads();
  float mu = (redA[0] + redA[1] + redA[2] + redA[3]) * (1.f / DX);
  float s2 = 0.f;
#pragma unroll
  for (int i = 0; i < 4; ++i) { float d = x[i] - mu; s2 += d * d; }
#pragma unroll
  for (int off = 32; off > 0; off >>= 1) s2 += __shfl_xor(s2, off);
  if ((tid & 63) == 0) redB[tid >> 6] = s2;
  __syncthreads();
  float var = (redB[0] + redB[1] + redB[2] + redB[3]) * (1.f / DX);
  float rstd = rsqrtf(var + 1e-5f);
#pragma unroll
  for (int i = 0; i < 4; ++i) {
    int c = tid + (i << 8);
    out[(size_t)t * DX + c] = (x[i] - mu) * rstd * g[c] + beta[c];
  }
}

extern "C" void kernel_launch(void* const* d_in, const int* in_sizes, int n_in,
                              void* d_out, int out_size, void* d_ws, size_t ws_size,
                              hipStream_t stream) {
  const float* q = (const float*)d_in[0];
  const float* k = (const float*)d_in[1];
  const float* v = (const float*)d_in[2];
  const int* mask = (const int*)d_in[3];
  const float* wq_w = (const float*)d_in[4];
  const float* wq_b = (const float*)d_in[5];
  const float* wk_w = (const float*)d_in[6];
  const float* wk_b = (const float*)d_in[7];
  const float* wv_w = (const float*)d_in[8];
  const float* wv_b = (const float*)d_in[9];
  const float* wo_w = (const float*)d_in[10];
  const float* wo_b = (const float*)d_in[11];
  const float* ln_g = (const float*)d_in[12];
  const float* ln_b = (const float*)d_in[13];

  float* out = (float*)d_out;
  float* attn = out + (size_t)NTOK * DX;  // second output, 134,217,728 f32

  // workspace carve (~82 MB total)
  ushort* qb   = (ushort*)d_ws;              // 4,194,304 elems each
  ushort* kb   = qb + 4194304;
  ushort* vb   = kb + 4194304;
  ushort* wt   = vb + 4194304;               // 4 x 1,048,576 (wq,wk,wv,wo)^T bf16
  ushort* Qh   = wt + 4 * 1048576;           // [b][h][l][dk]
  ushort* Kh   = Qh + 4194304;
  ushort* Vth  = Kh + 4194304;               // [b][h][dk][l]
  uint*  mpak  = (uint*)(Vth + 4194304);     // 262,144 words used
  ushort* aout = (ushort*)(mpak + 524288);   // [tok][h*64+dk] bf16
  float* proj  = (float*)(aout + 4194304);   // [tok][DX] f32

  pack_mask_k<<<(BB * LQ * LK) / 256, 256, 0, stream>>>(mask, mpak);
  convert_in_k<<<dim3((NTOK * DX) / 1024, 1, 3), 256, 0, stream>>>(q, k, v, qb, kb, vb);
  transpose_w_k<<<dim3(16, 16, 4), 256, 0, stream>>>(wq_w, wk_w, wv_w, wo_w, wt);
  gemm_qkv_k<<<dim3(16, 32, 3), 256, 0, stream>>>(qb, kb, vb, wt, wq_b, wk_b, wv_b,
                                                  Qh, Kh, Vth);
  attn_k<<<dim3(LQ / 64, NBH), 256, 0, stream>>>(Qh, Kh, Vth, mpak, attn, aout);
  gemm_out_k<<<dim3(16, 32), 256, 0, stream>>>(aout, wt + 3 * 1048576, proj);
  ln_k<<<NTOK, 256, 0, stream>>>(proj, q, wo_b, ln_g, ln_b, out);
}